// Round 7
// baseline (284.729 us; speedup 1.0000x reference)
//
#include <hip/hip_runtime.h>
#include <math.h>

#define B_    4
#define L_    4092
#define H_    8
#define DM    512
#define WS_   12
#define NW    681
#define NC    682            // 6-row output chunks per (b,h); L = 6*682
#define NC2   341            // chunk PAIRS (682 = 2*341)
#define EPS_  1e-5f
#define Z_ELEMS (B_*L_*DM)   // 8,380,416

typedef unsigned short u16;
typedef __attribute__((ext_vector_type(8))) short short8;
typedef __attribute__((ext_vector_type(4))) float floatx4;

__device__ __forceinline__ u16 f2bf(float f) {
    union { float f; unsigned u; } x; x.f = f;
    unsigned u = x.u;
    return (u16)((u + 0x7FFFu + ((u >> 16) & 1u)) >> 16);
}
__device__ __forceinline__ float bf2f(u16 h) {
    union { unsigned u; float f; } x; x.u = ((unsigned)h) << 16; return x.f;
}
__device__ __forceinline__ float lo16f(unsigned u) {
    union { unsigned x; float f; } a; a.x = u << 16; return a.f;
}
__device__ __forceinline__ float hi16f(unsigned u) {
    union { unsigned x; float f; } a; a.x = u & 0xffff0000u; return a.f;
}
// Dekker-style bf16 split: v = hi + lo + eps, |eps| <= 2^-18 |v|.
__device__ __forceinline__ void pack8_hl(float4 a, float4 b, short8& hi, short8& lo) {
    float v[8] = {a.x, a.y, a.z, a.w, b.x, b.y, b.z, b.w};
    #pragma unroll
    for (int i = 0; i < 8; ++i) {
        u16 h = f2bf(v[i]);
        hi[i] = (short)h;
        lo[i] = (short)f2bf(v[i] - bf2f(h));
    }
}

// ---------------------------------------------------------------------------
// K1: projection GEMM via hi/lo bf16 MFMA, fp32 Q/K outputs (R6-proven:
// absmax 0.03125). R6 residual: grid 512 = only 2 blocks/CU (no LDS, VGPR
// ~76) -> exposed memory latency, 3.2 TB/s vs 29 µs floor. Fix: grid 1024
// (4 blocks/CU), 2 tiles/wave. W-pack amortizes over 2 tiles (+23% issue,
// hidden under memory); all MFMA/store expressions identical to R6.
// ---------------------------------------------------------------------------
__global__ __launch_bounds__(256) void proj_kernel(
    const float* __restrict__ q, const float* __restrict__ k, const float* __restrict__ v,
    const float* __restrict__ Wq, const float* __restrict__ Wk, const float* __restrict__ Wv,
    float* __restrict__ Qf, float* __restrict__ Kf, u16* __restrict__ Vh)
{
    const int tensor = blockIdx.y;
    const float* __restrict__ X = (tensor == 0) ? q  : (tensor == 1) ? k  : v;
    const float* __restrict__ W = (tensor == 0) ? Wq : (tensor == 1) ? Wk : Wv;
    float* __restrict__ Yf      = (tensor == 0) ? Qf : Kf;
    const bool isV = (tensor == 2);

    const int t = threadIdx.x, lane = t & 63, wv = t >> 6;
    const int m = lane & 15, q3 = lane >> 4;

    short8 wfh[4][2], wfl[4][2];
    #pragma unroll
    for (int nt = 0; nt < 4; ++nt)
        #pragma unroll
        for (int kc = 0; kc < 2; ++kc) {
            const float* wp = W + (4 * m + nt) * 64 + kc * 32 + q3 * 8;
            pack8_hl(*(const float4*)wp, *(const float4*)(wp + 4), wfh[nt][kc], wfl[nt][kc]);
        }

    const int waveId = blockIdx.x * 4 + wv;        // 0..4095
    for (int tile = waveId; tile < 8184; tile += 4096) {
        const int rbase = tile * 16;
        const int r = rbase + m;
        const int bh = r / L_;
        const int l = r - bh * L_;
        const int b = bh >> 3, h = bh & 7;
        const float* xp = X + (((size_t)b * L_ + l) * H_ + h) * 64;
        short8 a0h, a0l, a1h, a1l;
        pack8_hl(*(const float4*)(xp + q3 * 8),      *(const float4*)(xp + q3 * 8 + 4),      a0h, a0l);
        pack8_hl(*(const float4*)(xp + 32 + q3 * 8), *(const float4*)(xp + 32 + q3 * 8 + 4), a1h, a1l);

        floatx4 acc[4];
        #pragma unroll
        for (int nt = 0; nt < 4; ++nt) {
            floatx4 c = {0.f, 0.f, 0.f, 0.f};
            c = __builtin_amdgcn_mfma_f32_16x16x32_bf16(a0h, wfh[nt][0], c, 0, 0, 0);
            c = __builtin_amdgcn_mfma_f32_16x16x32_bf16(a1h, wfh[nt][1], c, 0, 0, 0);
            c = __builtin_amdgcn_mfma_f32_16x16x32_bf16(a0h, wfl[nt][0], c, 0, 0, 0);
            c = __builtin_amdgcn_mfma_f32_16x16x32_bf16(a0l, wfh[nt][0], c, 0, 0, 0);
            c = __builtin_amdgcn_mfma_f32_16x16x32_bf16(a1h, wfl[nt][1], c, 0, 0, 0);
            c = __builtin_amdgcn_mfma_f32_16x16x32_bf16(a1l, wfh[nt][1], c, 0, 0, 0);
            acc[nt] = c;
        }
        #pragma unroll
        for (int reg = 0; reg < 4; ++reg) {
            const int row = rbase + q3 * 4 + reg;
            if (!isV) {
                float4 o4;
                o4.x = acc[0][reg]; o4.y = acc[1][reg];
                o4.z = acc[2][reg]; o4.w = acc[3][reg];
                *(float4*)(Yf + (size_t)row * 64 + 4 * m) = o4;
            } else {
                ushort4 o4;
                o4.x = f2bf(acc[0][reg]); o4.y = f2bf(acc[1][reg]);
                o4.z = f2bf(acc[2][reg]); o4.w = f2bf(acc[3][reg]);
                *(ushort4*)(Vh + (size_t)row * 64 + 4 * m) = o4;
            }
        }
    }
}

// ---------------------------------------------------------------------------
// K2a: fused window attention + overlap-add, S=2 super-chunks (R6 structure).
// R6 residual: LDS 49.2 KB -> 3 blocks/CU; PV issues 18x20 ops on 24/64
// useful lanes. Fixes: (1) V staged as RAW bf16 (u16) -> LDS 36.9 KB -> 4
// blocks/CU; staging V is a pure copy; exact unpack (shl/and) moves to PV.
// (2) PV kt-SPLIT: lanes 0-23 do kt 0-8, lanes 24-47 do kt 9-17 with weights
// shuffled from lane-24 (ks preserved: 24 = 6*4); partials combined by 16
// shuffle+adds. Combined weights wk[18] precomputed once (same expressions).
// Score chain (dots/shuffles/softmax) byte-identical to R6. Only the kt
// summation order of PV changes (fp32 reorder ~1e-7).
// ---------------------------------------------------------------------------
__global__ __launch_bounds__(256, 4) void attn_kernel(
    const float* __restrict__ Qf, const float* __restrict__ Kf, const u16* __restrict__ Vh,
    float* __restrict__ attn, float* __restrict__ xout)
{
    __shared__ alignas(16) float Ks[4][24][64];   // 24.6 KB
    __shared__ alignas(16) u16  Vs16[4][24][64];  // 12.3 KB

    const int c2 = blockIdx.x, b = blockIdx.y, hg = blockIdx.z;
    const int t = threadIdx.x, lane = t & 63, w = t >> 6;   // w = head-in-group
    const int h = hg * 4 + w;
    const int qq = lane >> 2, ks = lane & 3;
    const int bh = b * 8 + h;
    const int lbase = c2 * 12 - 6;                 // staged row 0 -> global row lbase

    // --- stage K (fp32) + V (raw bf16) for 4 heads x 24 rows, zero-fill OOB ---
    for (int i = t; i < 1536; i += 256) {          // 1536 = 4 heads * 24 rows * 16 seg4
        const int hh  = i / 384;
        const int rem = i - hh * 384;
        const int rr  = rem >> 4;
        const int cc  = (rem & 15) * 4;
        const int l = lbase + rr;
        float4 kf4 = make_float4(0.f, 0.f, 0.f, 0.f);
        ushort4 v4 = {0, 0, 0, 0};
        if (l >= 0 && l < L_) {
            const size_t base = ((size_t)(b * 8 + hg * 4 + hh) * L_ + l) * 64 + cc;
            kf4 = *(const float4*)(Kf + base);
            v4  = *(const ushort4*)(Vh + base);
        }
        *(float4*)&Ks[hh][rr][cc]   = kf4;
        *(ushort4*)&Vs16[hh][rr][cc] = v4;
    }
    __syncthreads();

    #pragma unroll
    for (int j = 0; j < 2; ++j) {
        const int c = c2 * 2 + j;
        const bool hasA = (c < NW), hasB = (c > 0);     // uniform per j-iteration
        const float scale = (hasA && hasB) ? 0.5f : 1.0f;
        const int koff = 6 * j;                          // staged-row offset of this chunk

        // Q segment for global row c*6+qq (zeros on invalid lanes -> s==0, finite)
        float4 qs0, qs1, qs2, qs3;
        const int qmax = hasA ? 12 : 6;
        if (qq < qmax) {
            const float* qp = Qf + ((size_t)bh * L_ + (c * 6 + qq)) * 64 + ks * 16;
            qs0 = *(const float4*)(qp);     qs1 = *(const float4*)(qp + 4);
            qs2 = *(const float4*)(qp + 8); qs3 = *(const float4*)(qp + 12);
        } else {
            qs0 = qs1 = qs2 = qs3 = make_float4(0.f, 0.f, 0.f, 0.f);
        }

        // --- unified dot pass vs the chunk's 18 staged K rows ---
        float s[18];
        #pragma unroll
        for (int kt = 0; kt < 18; ++kt) {
            const float* kp = &Ks[w][koff + kt][ks * 16];
            const float4 k0 = *(const float4*)(kp);
            const float4 k1 = *(const float4*)(kp + 4);
            const float4 k2 = *(const float4*)(kp + 8);
            const float4 k3 = *(const float4*)(kp + 12);
            s[kt] = qs0.x*k0.x + qs0.y*k0.y + qs0.z*k0.z + qs0.w*k0.w
                  + qs1.x*k1.x + qs1.y*k1.y + qs1.z*k1.z + qs1.w*k1.w
                  + qs2.x*k2.x + qs2.y*k2.y + qs2.z*k2.z + qs2.w*k2.w
                  + qs3.x*k3.x + qs3.y*k3.y + qs3.z*k3.z + qs3.w*k3.w;
        }
        #pragma unroll
        for (int kt = 0; kt < 18; ++kt) {
            s[kt] += __shfl_xor(s[kt], 1);
            s[kt] += __shfl_xor(s[kt], 2);
        }

        // --- softmax A: window c, over s[6..17] ---
        float eA[12], invA = 0.f;
        if (hasA) {
            float mxA = s[6];
            #pragma unroll
            for (int jj = 1; jj < 12; ++jj) mxA = fmaxf(mxA, s[6 + jj]);
            float sumA = 0.f;
            #pragma unroll
            for (int jj = 0; jj < 12; ++jj) { eA[jj] = __expf((s[6 + jj] - mxA) * 0.125f); sumA += eA[jj]; }
            invA = 1.0f / sumA;
            if (ks == 0 && qq < 12) {
                float* ao = attn + ((size_t)bh * NW + c) * 144 + qq * 12;
                float4 a0, a1, a2;
                a0.x = eA[0]*invA; a0.y = eA[1]*invA;  a0.z = eA[2]*invA;  a0.w = eA[3]*invA;
                a1.x = eA[4]*invA; a1.y = eA[5]*invA;  a1.z = eA[6]*invA;  a1.w = eA[7]*invA;
                a2.x = eA[8]*invA; a2.y = eA[9]*invA;  a2.z = eA[10]*invA; a2.w = eA[11]*invA;
                *(float4*)(ao)     = a0;
                *(float4*)(ao + 4) = a1;
                *(float4*)(ao + 8) = a2;
            }
        } else {
            #pragma unroll
            for (int jj = 0; jj < 12; ++jj) eA[jj] = 0.f;
        }

        // --- softmax B: window c-1 (this Q row acts as its row qq+6), s[0..11] ---
        float eB[12], invB = 0.f;
        if (hasB) {
            float mxB = s[0];
            #pragma unroll
            for (int jj = 1; jj < 12; ++jj) mxB = fmaxf(mxB, s[jj]);
            float sumB = 0.f;
            #pragma unroll
            for (int jj = 0; jj < 12; ++jj) { eB[jj] = __expf((s[jj] - mxB) * 0.125f); sumB += eB[jj]; }
            invB = 1.0f / sumB;
        } else {
            #pragma unroll
            for (int jj = 0; jj < 12; ++jj) eB[jj] = 0.f;
        }

        // --- combined overlap-add weights wk[18] (same expressions as R6 PV) ---
        float wk[18];
        #pragma unroll
        for (int kt = 0; kt < 18; ++kt) {
            const float wa = (kt >= 6) ? eA[kt - 6] * invA : 0.f;
            const float wb = (kt < 12) ? eB[kt] * invB : 0.f;
            wk[kt] = scale * (wa + wb);
        }
        // ship wk[9..17] of row (qq-6) to lanes 24..47 (ks preserved: 24=6*4)
        const int srcW = (lane >= 24 && lane < 48) ? lane - 24 : lane;
        #pragma unroll
        for (int kk = 0; kk < 9; ++kk)
            wk[9 + kk] = __shfl(wk[9 + kk], srcW);   // low lanes: self (unchanged)

        // --- PV kt-split: grp0 (lanes<24) kt 0..8, grp1 kt 9..17 ---
        const int grp = (lane < 24) ? 0 : 1;
        const u16* vrow = &Vs16[w][koff][0] + (grp ? 9 * 64 : 0) + ks * 16;
        float4 xo0 = make_float4(0.f,0.f,0.f,0.f), xo1 = xo0, xo2 = xo0, xo3 = xo0;
        #pragma unroll
        for (int kk = 0; kk < 9; ++kk) {
            const float wkv = grp ? wk[9 + kk] : wk[kk];
            const u16* vp = vrow + kk * 64;
            const uint4 ua = *(const uint4*)(vp);      // v[0..7]  bf16 pairs
            const uint4 ub = *(const uint4*)(vp + 8);  // v[8..15]
            xo0.x += wkv * lo16f(ua.x); xo0.y += wkv * hi16f(ua.x);
            xo0.z += wkv * lo16f(ua.y); xo0.w += wkv * hi16f(ua.y);
            xo1.x += wkv * lo16f(ua.z); xo1.y += wkv * hi16f(ua.z);
            xo1.z += wkv * lo16f(ua.w); xo1.w += wkv * hi16f(ua.w);
            xo2.x += wkv * lo16f(ub.x); xo2.y += wkv * hi16f(ub.x);
            xo2.z += wkv * lo16f(ub.y); xo2.w += wkv * hi16f(ub.y);
            xo3.x += wkv * lo16f(ub.z); xo3.y += wkv * hi16f(ub.z);
            xo3.z += wkv * lo16f(ub.w); xo3.w += wkv * hi16f(ub.w);
        }
        // combine: lanes<24 add the lane+24 partial (others add self; ignored)
        const int srcC = (lane < 24) ? lane + 24 : lane;
        xo0.x += __shfl(xo0.x, srcC); xo0.y += __shfl(xo0.y, srcC);
        xo0.z += __shfl(xo0.z, srcC); xo0.w += __shfl(xo0.w, srcC);
        xo1.x += __shfl(xo1.x, srcC); xo1.y += __shfl(xo1.y, srcC);
        xo1.z += __shfl(xo1.z, srcC); xo1.w += __shfl(xo1.w, srcC);
        xo2.x += __shfl(xo2.x, srcC); xo2.y += __shfl(xo2.y, srcC);
        xo2.z += __shfl(xo2.z, srcC); xo2.w += __shfl(xo2.w, srcC);
        xo3.x += __shfl(xo3.x, srcC); xo3.y += __shfl(xo3.y, srcC);
        xo3.z += __shfl(xo3.z, srcC); xo3.w += __shfl(xo3.w, srcC);

        if (qq < 6) {
            float* xp = xout + ((size_t)b * L_ + (c * 6 + qq)) * DM + h * 64 + ks * 16;
            *(float4*)(xp)      = xo0;
            *(float4*)(xp + 4)  = xo1;
            *(float4*)(xp + 8)  = xo2;
            *(float4*)(xp + 12) = xo3;
        }
    }
}

// ---------------------------------------------------------------------------
// K2b: residual + LayerNorm, streaming; 2 independent rows per wave (loads
// co-issued -> 2x memory-level parallelism), gamma/beta loaded once.
// Expressions identical to R6.
// ---------------------------------------------------------------------------
__global__ __launch_bounds__(512) void ln_kernel(
    const float* __restrict__ qres, const float* __restrict__ gamma,
    const float* __restrict__ beta, float* __restrict__ z)
{
    const int wv = threadIdx.x >> 6, lane = threadIdx.x & 63;
    const int row0 = (blockIdx.x * 8 + wv) * 2;            // 0..16366 (grid 1023)
    const int cc = lane * 8;

    float* xp0 = z + (size_t)row0 * DM + cc;
    float* xp1 = z + (size_t)(row0 + 1) * DM + cc;
    const float* qr0 = qres + (size_t)row0 * DM + cc;
    const float* qr1 = qres + (size_t)(row0 + 1) * DM + cc;

    float4 xa0 = *(const float4*)(xp0);
    float4 xb0 = *(const float4*)(xp0 + 4);
    float4 xa1 = *(const float4*)(xp1);
    float4 xb1 = *(const float4*)(xp1 + 4);
    const float4 ra0  = *(const float4*)qr0;
    const float4 rb0  = *(const float4*)(qr0 + 4);
    const float4 ra1  = *(const float4*)qr1;
    const float4 rb1  = *(const float4*)(qr1 + 4);
    const float4 ga = *(const float4*)(gamma + cc);
    const float4 gb = *(const float4*)(gamma + cc + 4);
    const float4 ba = *(const float4*)(beta + cc);
    const float4 bb = *(const float4*)(beta + cc + 4);

    xa0.x += ra0.x; xa0.y += ra0.y; xa0.z += ra0.z; xa0.w += ra0.w;
    xb0.x += rb0.x; xb0.y += rb0.y; xb0.z += rb0.z; xb0.w += rb0.w;
    xa1.x += ra1.x; xa1.y += ra1.y; xa1.z += ra1.z; xa1.w += ra1.w;
    xb1.x += rb1.x; xb1.y += rb1.y; xb1.z += rb1.z; xb1.w += rb1.w;

    float s10 = xa0.x + xa0.y + xa0.z + xa0.w + xb0.x + xb0.y + xb0.z + xb0.w;
    float s20 = xa0.x*xa0.x + xa0.y*xa0.y + xa0.z*xa0.z + xa0.w*xa0.w
              + xb0.x*xb0.x + xb0.y*xb0.y + xb0.z*xb0.z + xb0.w*xb0.w;
    float s11 = xa1.x + xa1.y + xa1.z + xa1.w + xb1.x + xb1.y + xb1.z + xb1.w;
    float s21 = xa1.x*xa1.x + xa1.y*xa1.y + xa1.z*xa1.z + xa1.w*xa1.w
              + xb1.x*xb1.x + xb1.y*xb1.y + xb1.z*xb1.z + xb1.w*xb1.w;
    #pragma unroll
    for (int off = 1; off < 64; off <<= 1) {
        s10 += __shfl_xor(s10, off, 64);
        s20 += __shfl_xor(s20, off, 64);
        s11 += __shfl_xor(s11, off, 64);
        s21 += __shfl_xor(s21, off, 64);
    }
    const float mu0  = s10 * (1.0f / 512.0f);
    const float var0 = s20 * (1.0f / 512.0f) - mu0 * mu0;
    const float inv0 = 1.0f / sqrtf(var0 + EPS_);
    const float mu1  = s11 * (1.0f / 512.0f);
    const float var1 = s21 * (1.0f / 512.0f) - mu1 * mu1;
    const float inv1 = 1.0f / sqrtf(var1 + EPS_);

    float4 oa, ob;
    oa.x = (xa0.x - mu0) * inv0 * ga.x + ba.x;
    oa.y = (xa0.y - mu0) * inv0 * ga.y + ba.y;
    oa.z = (xa0.z - mu0) * inv0 * ga.z + ba.z;
    oa.w = (xa0.w - mu0) * inv0 * ga.w + ba.w;
    ob.x = (xb0.x - mu0) * inv0 * gb.x + bb.x;
    ob.y = (xb0.y - mu0) * inv0 * gb.y + bb.y;
    ob.z = (xb0.z - mu0) * inv0 * gb.z + bb.z;
    ob.w = (xb0.w - mu0) * inv0 * gb.w + bb.w;
    *(float4*)(xp0)     = oa;
    *(float4*)(xp0 + 4) = ob;

    oa.x = (xa1.x - mu1) * inv1 * ga.x + ba.x;
    oa.y = (xa1.y - mu1) * inv1 * ga.y + ba.y;
    oa.z = (xa1.z - mu1) * inv1 * ga.z + ba.z;
    oa.w = (xa1.w - mu1) * inv1 * ga.w + ba.w;
    ob.x = (xb1.x - mu1) * inv1 * gb.x + bb.x;
    ob.y = (xb1.y - mu1) * inv1 * gb.y + bb.y;
    ob.z = (xb1.z - mu1) * inv1 * gb.z + bb.z;
    ob.w = (xb1.w - mu1) * inv1 * gb.w + bb.w;
    *(float4*)(xp1)     = oa;
    *(float4*)(xp1 + 4) = ob;
}

extern "C" void kernel_launch(void* const* d_in, const int* in_sizes, int n_in,
                              void* d_out, int out_size, void* d_ws, size_t ws_size,
                              hipStream_t stream) {
    const float* q     = (const float*)d_in[0];
    const float* k     = (const float*)d_in[1];
    const float* v     = (const float*)d_in[2];
    const float* Wq    = (const float*)d_in[3];
    const float* Wk    = (const float*)d_in[4];
    const float* Wv    = (const float*)d_in[5];
    const float* gamma = (const float*)d_in[6];
    const float* beta  = (const float*)d_in[7];

    float* z    = (float*)d_out;
    float* attn = (float*)d_out + Z_ELEMS;

    // Workspace: Qf fp32 (33.5 MB) + Kf fp32 (33.5 MB) + Vh bf16 (16.8 MB)
    const size_t plane = (size_t)B_ * H_ * L_ * 64;   // 8,380,416 elements
    float* Qf = (float*)d_ws;
    float* Kf = Qf + plane;
    u16*  Vh  = (u16*)(Kf + plane);

    proj_kernel<<<dim3(1024, 3, 1), 256, 0, stream>>>(q, k, v, Wq, Wk, Wv, Qf, Kf, Vh);
    attn_kernel<<<dim3(NC2, B_, 2), 256, 0, stream>>>(Qf, Kf, Vh, attn, z);
    ln_kernel<<<dim3(1023, 1, 1), 512, 0, stream>>>(q, gamma, beta, z);
}